// Round 10
// baseline (635.820 us; speedup 1.0000x reference)
//
#include <hip/hip_runtime.h>
#include <cstdint>

typedef __attribute__((ext_vector_type(8))) short short8;
typedef __attribute__((ext_vector_type(4))) float f32x4;
typedef unsigned short ushort_t;

static constexpr int NN = 16384, FF = 256, GG = 64, EE = 131072, LL = 3;
static constexpr int HIDN = 512, IU = 32640, IN1 = 33408;
#define EPSV 1e-5f

__device__ inline unsigned short bf16r(float v) {
  unsigned u = __float_as_uint(v);
  u += 0x7FFFu + ((u >> 16) & 1u);
  return (unsigned short)(u >> 16);
}

// ---------------- zero deg+cnt ----------------
__global__ __launch_bounds__(256) void k_zero(int* __restrict__ p) {
  int i = blockIdx.x * 256 + threadIdx.x;
  if (i < 16448) p[i] = 0;  // deg[16384] + cnt[64] contiguous
}

// ---------------- deg histogram + cnt (LDS histogram) ----------------
__global__ __launch_bounds__(256) void k_hist(const int* __restrict__ dst,
                                              const int* __restrict__ batch,
                                              int* __restrict__ deg, int* __restrict__ cnt) {
  __shared__ int hist[64];
  int bx = blockIdx.x, t = threadIdx.x;
  if (bx < 512) {
    int e = bx * 256 + t;
    atomicAdd(&deg[dst[e]], 1);
  } else {
    if (t < 64) hist[t] = 0;
    __syncthreads();
    int4 v = ((const int4*)batch)[(bx - 512) * 256 + t];
    int a[4] = {v.x, v.y, v.z, v.w};
    int cur = a[0], run = 1;
#pragma unroll
    for (int j = 1; j < 4; ++j) {
      if (a[j] == cur) run++;
      else { atomicAdd(&hist[cur], run); cur = a[j]; run = 1; }
    }
    atomicAdd(&hist[cur], run);
    __syncthreads();
    if (t < 64 && hist[t]) atomicAdd(&cnt[t], hist[t]);
  }
}

// ---------------- conv layer via MFMA bf16-pair: C = deg*(A@W+b), fused pooling ------
// grid (256, 2) M-MAJOR: blocks (mb,0) and (mb,1) are both dispatch#=mb (mod 8) ->
// same XCD -> A-tile's 2nd read hits that XCD's L2 (was 2x HBM with n-major grid).
__global__ __launch_bounds__(256, 2) void k_conv(const float* __restrict__ A,
                                                 const float* __restrict__ W,
                                                 const float* __restrict__ bias,
                                                 const int* __restrict__ deg,
                                                 float* __restrict__ C,
                                                 float* __restrict__ pooled_p, int lofs) {
  __shared__ __align__(16) unsigned short Ah[64][72], Al[64][72];
  __shared__ __align__(16) unsigned short Bh[128][72], Bl[128][72];
  int mb = blockIdx.x;
  int n0 = blockIdx.y * 128, m0 = mb * 64;
  int t = threadIdx.x;
  int w = t >> 6, l = t & 63;
  int wn = w * 32;
  int lr = l & 15, lg = l >> 4;
  f32x4 acc[4][2];
#pragma unroll
  for (int fm = 0; fm < 4; ++fm)
#pragma unroll
    for (int fn = 0; fn < 2; ++fn) acc[fm][fn] = (f32x4){0.f, 0.f, 0.f, 0.f};

  int am = t >> 2, aq = t & 3;
  int bkp = t & 3, bnf = (t >> 2) & 31, brr = t >> 7;

  for (int ks = 0; ks < 4; ++ks) {
    int k0 = ks * 64;
    if (ks) __syncthreads();
    {
      const float* ap = A + (size_t)(m0 + am) * FF + k0;
#pragma unroll
      for (int i = 0; i < 4; ++i) {
        int k = aq * 4 + i * 16;
        float4 v = *(const float4*)(ap + k);
        const float* vf = (const float*)&v;
        unsigned short h[4], lo[4];
#pragma unroll
        for (int j = 0; j < 4; ++j) {
          h[j] = bf16r(vf[j]);
          lo[j] = bf16r(vf[j] - __uint_as_float((unsigned)h[j] << 16));
        }
        *(uint2*)&Ah[am][k] = make_uint2((unsigned)h[0] | ((unsigned)h[1] << 16),
                                         (unsigned)h[2] | ((unsigned)h[3] << 16));
        *(uint2*)&Al[am][k] = make_uint2((unsigned)lo[0] | ((unsigned)lo[1] << 16),
                                         (unsigned)lo[2] | ((unsigned)lo[3] << 16));
      }
    }
#pragma unroll
    for (int r2 = 0; r2 < 4; ++r2) {
      int k = 2 * bkp + 8 * (brr * 4 + r2);
      const float* wp = W + (size_t)(k0 + k) * FF + n0 + bnf * 4;
      float4 va = *(const float4*)wp;
      float4 vb = *(const float4*)(wp + FF);
      const float* fa = (const float*)&va;
      const float* fb = (const float*)&vb;
#pragma unroll
      for (int j = 0; j < 4; ++j) {
        unsigned short ha = bf16r(fa[j]), hb = bf16r(fb[j]);
        unsigned short la = bf16r(fa[j] - __uint_as_float((unsigned)ha << 16));
        unsigned short lb = bf16r(fb[j] - __uint_as_float((unsigned)hb << 16));
        int n = bnf * 4 + j;
        *(unsigned*)&Bh[n][k] = (unsigned)ha | ((unsigned)hb << 16);
        *(unsigned*)&Bl[n][k] = (unsigned)la | ((unsigned)lb << 16);
      }
    }
    __syncthreads();
#pragma unroll
    for (int k2 = 0; k2 < 2; ++k2) {
      int kk = k2 * 32 + lg * 8;
      short8 afh[4], afl[4], bfh[2], bfl[2];
#pragma unroll
      for (int fm = 0; fm < 4; ++fm) {
        afh[fm] = *(const short8*)&Ah[fm * 16 + lr][kk];
        afl[fm] = *(const short8*)&Al[fm * 16 + lr][kk];
      }
#pragma unroll
      for (int fn = 0; fn < 2; ++fn) {
        bfh[fn] = *(const short8*)&Bh[wn + fn * 16 + lr][kk];
        bfl[fn] = *(const short8*)&Bl[wn + fn * 16 + lr][kk];
      }
#pragma unroll
      for (int fm = 0; fm < 4; ++fm)
#pragma unroll
        for (int fn = 0; fn < 2; ++fn) {
          acc[fm][fn] = __builtin_amdgcn_mfma_f32_16x16x32_bf16(afl[fm], bfh[fn], acc[fm][fn], 0, 0, 0);
          acc[fm][fn] = __builtin_amdgcn_mfma_f32_16x16x32_bf16(afh[fm], bfl[fn], acc[fm][fn], 0, 0, 0);
          acc[fm][fn] = __builtin_amdgcn_mfma_f32_16x16x32_bf16(afh[fm], bfh[fn], acc[fm][fn], 0, 0, 0);
        }
    }
  }
  float degf[4][4];
#pragma unroll
  for (int fm = 0; fm < 4; ++fm)
#pragma unroll
    for (int r = 0; r < 4; ++r)
      degf[fm][r] = (float)(deg[m0 + fm * 16 + lg * 4 + r] + 1);  // +1 self loop
  int g = mb >> 2, sub = mb & 3;
#pragma unroll
  for (int fn = 0; fn < 2; ++fn) {
    int col = n0 + wn + fn * 16 + lr;
    float bb = bias[col];
    float cs = 0.f;
#pragma unroll
    for (int fm = 0; fm < 4; ++fm) {
      const float* av = (const float*)&acc[fm][fn];
#pragma unroll
      for (int r = 0; r < 4; ++r) {
        int row = m0 + fm * 16 + lg * 4 + r;
        float v = (av[r] + bb) * degf[fm][r];
        if (C) C[(size_t)row * FF + col] = v;
        cs += v;
      }
    }
    cs += __shfl_xor(cs, 16);
    cs += __shfl_xor(cs, 32);
    if (lg == 0)
      pooled_p[((size_t)sub * 64 + g) * (FF * LL) + lofs + col] = cs;
  }
}

// ---------------- front BN: xt (blocks 0..255, 1024 thr) + pooled (blocks 256..267) ---
__global__ __launch_bounds__(1024, 1) void k_bn_front(const float* __restrict__ x,
                                                      const float* __restrict__ bn_g,
                                                      const float* __restrict__ bn_b,
                                                      const float* __restrict__ pooled_p,
                                                      const int* __restrict__ cnt,
                                                      const float* __restrict__ bnh_g,
                                                      const float* __restrict__ bnh_b,
                                                      ushort_t* __restrict__ zh,
                                                      ushort_t* __restrict__ zl) {
  if (blockIdx.x < 256) {
    __shared__ float sb1[16][256], sb2[16][256];
    __shared__ float rsA[256], bbA[256];
    int i = blockIdx.x, t = threadIdx.x;
    int jq = t & 63, gq = t >> 6;
    int j4 = jq * 4;
    float4 vals[4];
    float s1[4] = {}, s2[4] = {};
#pragma unroll
    for (int r = 0; r < 4; ++r) {
      int g = gq * 4 + r;
      float4 vv = *(const float4*)(x + (size_t)(g * 256 + i) * FF + j4);
      vals[r] = vv;
      s1[0] += vv.x; s2[0] += vv.x * vv.x;
      s1[1] += vv.y; s2[1] += vv.y * vv.y;
      s1[2] += vv.z; s2[2] += vv.z * vv.z;
      s1[3] += vv.w; s2[3] += vv.w * vv.w;
    }
    *(float4*)&sb1[gq][j4] = make_float4(s1[0], s1[1], s1[2], s1[3]);
    *(float4*)&sb2[gq][j4] = make_float4(s2[0], s2[1], s2[2], s2[3]);
    __syncthreads();
    if (t < 256) {
      int j = t;
      float S1 = 0.f, S2 = 0.f;
#pragma unroll
      for (int q = 0; q < 16; ++q) { S1 += sb1[q][j]; S2 += sb2[q][j]; }
      float m = S1 * (1.f / 64.f);
      float var = S2 * (1.f / 64.f) - m * m;
      float rs = 0.f, bb = 0.f;
      if (j > i) {
        int p = i * 255 - (i * (i - 1)) / 2 + (j - i - 1);
        rs = rsqrtf(var + EPSV) * bn_g[p];
        bb = bn_b[p] - m * rs;
      }
      rsA[j] = rs;
      bbA[j] = bb;
    }
    __syncthreads();
    int P0 = i * 255 - (i * (i - 1)) / 2 - i - 1;  // p = P0 + j
#pragma unroll
    for (int r = 0; r < 4; ++r) {
      int g = gq * 4 + r;
      size_t base = (size_t)g * IN1 + P0;
      const float* vf = (const float*)&vals[r];
#pragma unroll
      for (int jj = 0; jj < 4; ++jj) {
        int j = j4 + jj;
        if (j > i) {
          float f = vf[jj] * rsA[j] + bbA[j];
          unsigned short h = bf16r(f);
          zh[base + j] = h;
          zl[base + j] = bf16r(f - __uint_as_float((unsigned)h << 16));
        }
      }
    }
  } else {
    __shared__ float pb1[4][64], pb2[4][64], prs[64], pbb[64];
    int t = threadIdx.x;
    if (t >= 256) return;
    int bx = blockIdx.x - 256;
    int ql = t & 63, gq = t >> 6;
    int q = bx * 64 + ql;
    float vals[16];
    float s1 = 0.f, s2 = 0.f;
#pragma unroll
    for (int gg = 0; gg < 16; ++gg) {
      int g = gq * 16 + gg;
      float v = (pooled_p[((size_t)0 * 64 + g) * (FF * LL) + q] +
                 pooled_p[((size_t)1 * 64 + g) * (FF * LL) + q] +
                 pooled_p[((size_t)2 * 64 + g) * (FF * LL) + q] +
                 pooled_p[((size_t)3 * 64 + g) * (FF * LL) + q]) / (float)cnt[g];
      vals[gg] = v;
      s1 += v;
      s2 += v * v;
    }
    pb1[gq][ql] = s1;
    pb2[gq][ql] = s2;
    __syncthreads();
    if (t < 64) {
      float S1 = pb1[0][t] + pb1[1][t] + pb1[2][t] + pb1[3][t];
      float S2 = pb2[0][t] + pb2[1][t] + pb2[2][t] + pb2[3][t];
      float m = S1 * (1.f / 64.f);
      float var = S2 * (1.f / 64.f) - m * m;
      int qq = bx * 64 + t;
      float rs = rsqrtf(var + EPSV) * bnh_g[qq];
      prs[t] = rs;
      pbb[t] = bnh_b[qq] - m * rs;
    }
    __syncthreads();
#pragma unroll
    for (int gg = 0; gg < 16; ++gg) {
      int g = gq * 16 + gg;
      float f = vals[gg] * prs[ql] + pbb[ql];
      unsigned short h = bf16r(f);
      zh[(size_t)g * IN1 + IU + q] = h;
      zl[(size_t)g * IN1 + IU + q] = bf16r(f - __uint_as_float((unsigned)h << 16));
    }
  }
}

// ---------------- w1 GEMM via MFMA (S=128 -> 1024 blocks = 4/CU) ----------------
__global__ __launch_bounds__(256, 4) void k_w1(const ushort_t* __restrict__ zh,
                                               const ushort_t* __restrict__ zl,
                                               const float* __restrict__ W,
                                               float* __restrict__ partial) {
  __shared__ __align__(16) unsigned short Zh[64][72], Zl[64][72];
  __shared__ __align__(16) unsigned short Wh[64][72], Wl[64][72];
  int nb = blockIdx.x, s = blockIdx.y;
  int t = threadIdx.x;
  int w = t >> 6, l = t & 63, lr = l & 15, lg = l >> 4;
  int ncol = nb * 64 + w * 16 + lr;
  f32x4 acc[4];
#pragma unroll
  for (int mt = 0; mt < 4; ++mt) acc[mt] = (f32x4){0.f, 0.f, 0.f, 0.f};

  for (int c = s; c < 522; c += 128) {  // 33408 = 522*64
    int p0 = c * 64;
    if (c != s) __syncthreads();
#pragma unroll
    for (int it = 0; it < 2; ++it) {
      int idx = it * 256 + t;
      int g = idx >> 3, kq = idx & 7;
      *(uint4*)&Zh[g][kq * 8] = *(const uint4*)(zh + (size_t)g * IN1 + p0 + kq * 8);
      *(uint4*)&Zl[g][kq * 8] = *(const uint4*)(zl + (size_t)g * IN1 + p0 + kq * 8);
    }
#pragma unroll
    for (int it = 0; it < 2; ++it) {
      int idx = it * 256 + t;
      int kp = idx >> 4, cg = idx & 15;
      int k = kp * 2;
      const float* wp = W + (size_t)(p0 + k) * HIDN + nb * 64 + cg * 4;
      float4 va = *(const float4*)wp;
      float4 vb = *(const float4*)(wp + HIDN);
      const float* fa = (const float*)&va;
      const float* fb = (const float*)&vb;
#pragma unroll
      for (int j = 0; j < 4; ++j) {
        unsigned ua = __float_as_uint(fa[j]);
        unsigned ub = __float_as_uint(fb[j]);
        unsigned short ha = (unsigned short)(ua >> 16);
        unsigned short hb = (unsigned short)(ub >> 16);
        unsigned short la = bf16r(fa[j] - __uint_as_float(ua & 0xFFFF0000u));
        unsigned short lb = bf16r(fb[j] - __uint_as_float(ub & 0xFFFF0000u));
        int col = cg * 4 + j;
        *(unsigned*)&Wh[col][k] = (unsigned)ha | ((unsigned)hb << 16);
        *(unsigned*)&Wl[col][k] = (unsigned)la | ((unsigned)lb << 16);
      }
    }
    __syncthreads();
#pragma unroll
    for (int k2 = 0; k2 < 2; ++k2) {
      int kloc = k2 * 32 + lg * 8;
      short8 bh = *(const short8*)&Wh[w * 16 + lr][kloc];
      short8 bl = *(const short8*)&Wl[w * 16 + lr][kloc];
#pragma unroll
      for (int mt = 0; mt < 4; ++mt) {
        short8 ah = *(const short8*)&Zh[mt * 16 + lr][kloc];
        short8 al = *(const short8*)&Zl[mt * 16 + lr][kloc];
        acc[mt] = __builtin_amdgcn_mfma_f32_16x16x32_bf16(al, bh, acc[mt], 0, 0, 0);
        acc[mt] = __builtin_amdgcn_mfma_f32_16x16x32_bf16(ah, bl, acc[mt], 0, 0, 0);
        acc[mt] = __builtin_amdgcn_mfma_f32_16x16x32_bf16(ah, bh, acc[mt], 0, 0, 0);
      }
    }
  }
#pragma unroll
  for (int mt = 0; mt < 4; ++mt) {
    const float* av = (const float*)&acc[mt];
#pragma unroll
    for (int r = 0; r < 4; ++r) {
      int g = mt * 16 + lg * 4 + r;
      partial[((size_t)s * 64 + g) * HIDN + ncol] = av[r];
    }
  }
}

// ---------------- fused reduce(S)+bias+BN+ReLU: m1b = relu(BN(sum partial + b)) ------
// grid N/64 x 256 thr: c=t&63 (col), gq=t>>6 owns 16 g-rows.
__global__ __launch_bounds__(256) void k_rbn(const float* __restrict__ partial,
                                             const float* __restrict__ bias,
                                             const float* __restrict__ gamma,
                                             const float* __restrict__ beta,
                                             float* __restrict__ out, int S, int N) {
  __shared__ float sb1[4][64], sb2[4][64], rsA[64], bbA[64];
  int t = threadIdx.x;
  int c = t & 63, gq = t >> 6;
  int col = blockIdx.x * 64 + c;
  float acc[16];
  float bb = bias[col];
  float s1 = 0.f, s2 = 0.f;
#pragma unroll
  for (int gg = 0; gg < 16; ++gg) {
    int g = gq * 16 + gg;
    float a = bb;
    for (int s = 0; s < S; ++s) a += partial[((size_t)s * 64 + g) * N + col];
    acc[gg] = a;
    s1 += a;
    s2 += a * a;
  }
  sb1[gq][c] = s1;
  sb2[gq][c] = s2;
  __syncthreads();
  if (t < 64) {
    float S1 = sb1[0][t] + sb1[1][t] + sb1[2][t] + sb1[3][t];
    float S2 = sb2[0][t] + sb2[1][t] + sb2[2][t] + sb2[3][t];
    float m = S1 * (1.f / 64.f);
    float var = S2 * (1.f / 64.f) - m * m;
    int cc = blockIdx.x * 64 + t;
    float rs = rsqrtf(var + EPSV) * gamma[cc];
    rsA[t] = rs;
    bbA[t] = beta[cc] - m * rs;
  }
  __syncthreads();
#pragma unroll
  for (int gg = 0; gg < 16; ++gg) {
    int g = gq * 16 + gg;
    out[(size_t)g * N + col] = fmaxf(acc[gg] * rsA[c] + bbA[c], 0.f);
  }
}

// ---------------- fused small MLP layer: out = relu(BN(Z@W + b)), M=64 ---------------
__global__ __launch_bounds__(256, 2) void k_mlp_small(const float* __restrict__ Z,
                                                      const float* __restrict__ W,
                                                      const float* __restrict__ bias,
                                                      const float* __restrict__ gamma,
                                                      const float* __restrict__ beta,
                                                      float* __restrict__ out, int K, int N) {
  __shared__ float Ws[512 * 16];       // K<=512 rows x 16 cols
  __shared__ float zl[64][132];
  __shared__ float sb1[16][17], sb2[16][17];
  int t = threadIdx.x;
  int h0 = blockIdx.x * 16;
  for (int idx = t; idx < K * 4; idx += 256) {
    int r = idx >> 2, q = idx & 3;
    *(float4*)&Ws[r * 16 + q * 4] = *(const float4*)(W + (size_t)r * N + h0 + q * 4);
  }
  int c = t & 15, gq = t >> 4;         // col c, row-group gq (4 rows each)
  float acc[4] = {};
  for (int ch = 0; ch < K; ch += 128) {
    for (int idx = t; idx < 64 * 32; idx += 256) {
      int g = idx >> 5, kq = idx & 31;
      *(float4*)&zl[g][kq * 4] = *(const float4*)(Z + (size_t)g * K + ch + kq * 4);
    }
    __syncthreads();
#pragma unroll 8
    for (int kk = 0; kk < 128; ++kk) {
      float w = Ws[(ch + kk) * 16 + c];
#pragma unroll
      for (int i = 0; i < 4; ++i) acc[i] = fmaf(zl[gq * 4 + i][kk], w, acc[i]);
    }
    __syncthreads();
  }
  float bb = bias[h0 + c];
  float s1 = 0.f, s2 = 0.f;
#pragma unroll
  for (int i = 0; i < 4; ++i) {
    acc[i] += bb;
    s1 += acc[i];
    s2 += acc[i] * acc[i];
  }
  sb1[gq][c] = s1;
  sb2[gq][c] = s2;
  __syncthreads();
  float S1 = 0.f, S2 = 0.f;
#pragma unroll
  for (int q = 0; q < 16; ++q) { S1 += sb1[q][c]; S2 += sb2[q][c]; }
  float m = S1 * (1.f / 64.f);
  float var = S2 * (1.f / 64.f) - m * m;
  float rs = rsqrtf(var + EPSV) * gamma[h0 + c];
  float be = beta[h0 + c];
#pragma unroll
  for (int i = 0; i < 4; ++i)
    out[(size_t)(gq * 4 + i) * N + h0 + c] = fmaxf((acc[i] - m) * rs + be, 0.f);
}

// ---------------- final: out = A @ w4 + b4, [64,256]@[256,2], wave-parallel ----------
__global__ __launch_bounds__(256) void k_final(const float* __restrict__ A,
                                               const float* __restrict__ w4,
                                               const float* __restrict__ b4,
                                               float* __restrict__ out) {
  __shared__ float w4l[512];
  int t = threadIdx.x;
  w4l[t] = w4[t];
  w4l[256 + t] = w4[256 + t];
  __syncthreads();
  int w = t >> 6, l = t & 63;
  for (int g = w * 16; g < w * 16 + 16; ++g) {
    float4 av = *(const float4*)(A + (size_t)g * 256 + l * 4);
    float c0 = av.x * w4l[(l * 4 + 0) * 2] + av.y * w4l[(l * 4 + 1) * 2] +
               av.z * w4l[(l * 4 + 2) * 2] + av.w * w4l[(l * 4 + 3) * 2];
    float c1 = av.x * w4l[(l * 4 + 0) * 2 + 1] + av.y * w4l[(l * 4 + 1) * 2 + 1] +
               av.z * w4l[(l * 4 + 2) * 2 + 1] + av.w * w4l[(l * 4 + 3) * 2 + 1];
#pragma unroll
    for (int o = 32; o > 0; o >>= 1) {
      c0 += __shfl_xor(c0, o);
      c1 += __shfl_xor(c1, o);
    }
    if (l == 0) {
      out[g * 2 + 0] = c0 + b4[0];
      out[g * 2 + 1] = c1 + b4[1];
    }
  }
}

extern "C" void kernel_launch(void* const* d_in, const int* in_sizes, int n_in,
                              void* d_out, int out_size, void* d_ws, size_t ws_size,
                              hipStream_t stream) {
  const float* x = (const float*)d_in[0];
  const int* edge = (const int*)d_in[1];
  const int* batch = (const int*)d_in[2];
  // d_in[3],[4] lin_src_w/b: dead. d_in[7],[8] att_w/b: dead (softmax over singleton = 1).
  const float* lin_dst_w = (const float*)d_in[5];
  const float* lin_dst_b = (const float*)d_in[6];
  const float* bn_g = (const float*)d_in[9];
  const float* bn_b = (const float*)d_in[10];
  const float* bnh_g = (const float*)d_in[11];
  const float* bnh_b = (const float*)d_in[12];
  const float* w1 = (const float*)d_in[13];
  const float* b1 = (const float*)d_in[14];
  const float* g1 = (const float*)d_in[15];
  const float* be1 = (const float*)d_in[16];
  const float* w2 = (const float*)d_in[17];
  const float* b2 = (const float*)d_in[18];
  const float* g2 = (const float*)d_in[19];
  const float* be2 = (const float*)d_in[20];
  const float* w3 = (const float*)d_in[21];
  const float* b3 = (const float*)d_in[22];
  const float* g3 = (const float*)d_in[23];
  const float* be3 = (const float*)d_in[24];
  const float* w4 = (const float*)d_in[25];
  const float* b4 = (const float*)d_in[26];
  const int* dstp = edge + EE;  // edge_index[1]

  char* ws = (char*)d_ws;
  int* deg = (int*)(ws);                                     // 64 KB (+cnt adjacent)
  int* cnt = (int*)(ws + 65536);                             // 256 B
  float* bufA = (float*)(ws + 131072);                       // 16 MiB
  float* bufB = (float*)(ws + 131072 + 16777216);            // 16 MiB
  float* pooled_p = (float*)(ws + 131072 + 2 * 16777216);    // 4*64*768*4 = 786,432 B
  char* tail = ws + 131072 + 2 * 16777216 + 786432;
  float* m1b = (float*)(tail);                               // 64x512
  float* m2b = (float*)(tail + 131072);                      // 64x256
  float* m3b = (float*)(tail + 131072 + 65536);
  // z bf16 pairs live in bufA (h1 region, dead after conv2; h3 store skipped)
  ushort_t* zh = (ushort_t*)bufA;                            // 64*33408*2 = 4.28 MB
  ushort_t* zlp = zh + (size_t)64 * IN1;                     // 4.28 MB
  float* partial = bufB;  // S=128: 128*64*512*4 = 16,777,216 B == bufB exactly

  k_zero<<<65, 256, 0, stream>>>(deg);
  k_hist<<<528, 256, 0, stream>>>(dstp, batch, deg, cnt);

  // ---- 3 conv layers (MFMA bf16-pair), m-major grid for XCD L2 reuse of A ----
  k_conv<<<dim3(256, 2), 256, 0, stream>>>(x, lin_dst_w, lin_dst_b, deg, bufA, pooled_p, 0);
  k_conv<<<dim3(256, 2), 256, 0, stream>>>(bufA, lin_dst_w + (size_t)FF * FF,
                                           lin_dst_b + FF, deg, bufB, pooled_p, FF);
  k_conv<<<dim3(256, 2), 256, 0, stream>>>(bufB, lin_dst_w + (size_t)2 * FF * FF,
                                           lin_dst_b + 2 * FF, deg, (float*)nullptr,
                                           pooled_p, 2 * FF);

  // ---- z = [BN(xt) | BN(sum pooled/cnt)] as bf16 hi/lo (one kernel, 268 blocks) ----
  k_bn_front<<<268, 1024, 0, stream>>>(x, bn_g, bn_b, pooled_p, cnt, bnh_g, bnh_b, zh, zlp);

  // ---- MLP ----
  k_w1<<<dim3(8, 128), 256, 0, stream>>>(zh, zlp, w1, partial);
  k_rbn<<<8, 256, 0, stream>>>(partial, b1, g1, be1, m1b, 128, HIDN);

  k_mlp_small<<<16, 256, 0, stream>>>(m1b, w2, b2, g2, be2, m2b, HIDN, 256);
  k_mlp_small<<<16, 256, 0, stream>>>(m2b, w3, b3, g3, be3, m3b, 256, 256);

  k_final<<<1, 256, 0, stream>>>(m3b, w4, b4, (float*)d_out);
}

// Round 11
// 187.280 us; speedup vs baseline: 3.3950x; 3.3950x over previous
//
#include <hip/hip_runtime.h>
#include <cstdint>

typedef __attribute__((ext_vector_type(8))) short short8;
typedef __attribute__((ext_vector_type(4))) float f32x4;
typedef unsigned short ushort_t;

static constexpr int NN = 16384, FF = 256, GG = 64, EE = 131072, LL = 3;
static constexpr int HIDN = 512, IU = 32640, IN1 = 33408;
#define EPSV 1e-5f

__device__ inline unsigned short bf16r(float v) {
  unsigned u = __float_as_uint(v);
  u += 0x7FFFu + ((u >> 16) & 1u);
  return (unsigned short)(u >> 16);
}

// ---------------- zero deg+cnt ----------------
__global__ __launch_bounds__(256) void k_zero(int* __restrict__ p) {
  int i = blockIdx.x * 256 + threadIdx.x;
  if (i < 16448) p[i] = 0;  // deg[16384] + cnt[64] contiguous
}

// ---------------- deg histogram + cnt (LDS histogram) ----------------
__global__ __launch_bounds__(256) void k_hist(const int* __restrict__ dst,
                                              const int* __restrict__ batch,
                                              int* __restrict__ deg, int* __restrict__ cnt) {
  __shared__ int hist[64];
  int bx = blockIdx.x, t = threadIdx.x;
  if (bx < 512) {
    int e = bx * 256 + t;
    atomicAdd(&deg[dst[e]], 1);
  } else {
    if (t < 64) hist[t] = 0;
    __syncthreads();
    int4 v = ((const int4*)batch)[(bx - 512) * 256 + t];
    int a[4] = {v.x, v.y, v.z, v.w};
    int cur = a[0], run = 1;
#pragma unroll
    for (int j = 1; j < 4; ++j) {
      if (a[j] == cur) run++;
      else { atomicAdd(&hist[cur], run); cur = a[j]; run = 1; }
    }
    atomicAdd(&hist[cur], run);
    __syncthreads();
    if (t < 64 && hist[t]) atomicAdd(&cnt[t], hist[t]);
  }
}

// ---------------- conv layer via MFMA bf16-pair: C = deg*(A@W+b), fused pooling ------
// grid (256, 2) M-MAJOR: blocks (mb,0) and (mb,1) land on the same XCD ->
// A-tile's 2nd read hits that XCD's L2.
__global__ __launch_bounds__(256, 2) void k_conv(const float* __restrict__ A,
                                                 const float* __restrict__ W,
                                                 const float* __restrict__ bias,
                                                 const int* __restrict__ deg,
                                                 float* __restrict__ C,
                                                 float* __restrict__ pooled_p, int lofs) {
  __shared__ __align__(16) unsigned short Ah[64][72], Al[64][72];
  __shared__ __align__(16) unsigned short Bh[128][72], Bl[128][72];
  int mb = blockIdx.x;
  int n0 = blockIdx.y * 128, m0 = mb * 64;
  int t = threadIdx.x;
  int w = t >> 6, l = t & 63;
  int wn = w * 32;
  int lr = l & 15, lg = l >> 4;
  f32x4 acc[4][2];
#pragma unroll
  for (int fm = 0; fm < 4; ++fm)
#pragma unroll
    for (int fn = 0; fn < 2; ++fn) acc[fm][fn] = (f32x4){0.f, 0.f, 0.f, 0.f};

  int am = t >> 2, aq = t & 3;
  int bkp = t & 3, bnf = (t >> 2) & 31, brr = t >> 7;

  for (int ks = 0; ks < 4; ++ks) {
    int k0 = ks * 64;
    if (ks) __syncthreads();
    {
      const float* ap = A + (size_t)(m0 + am) * FF + k0;
#pragma unroll
      for (int i = 0; i < 4; ++i) {
        int k = aq * 4 + i * 16;
        float4 v = *(const float4*)(ap + k);
        const float* vf = (const float*)&v;
        unsigned short h[4], lo[4];
#pragma unroll
        for (int j = 0; j < 4; ++j) {
          h[j] = bf16r(vf[j]);
          lo[j] = bf16r(vf[j] - __uint_as_float((unsigned)h[j] << 16));
        }
        *(uint2*)&Ah[am][k] = make_uint2((unsigned)h[0] | ((unsigned)h[1] << 16),
                                         (unsigned)h[2] | ((unsigned)h[3] << 16));
        *(uint2*)&Al[am][k] = make_uint2((unsigned)lo[0] | ((unsigned)lo[1] << 16),
                                         (unsigned)lo[2] | ((unsigned)lo[3] << 16));
      }
    }
#pragma unroll
    for (int r2 = 0; r2 < 4; ++r2) {
      int k = 2 * bkp + 8 * (brr * 4 + r2);
      const float* wp = W + (size_t)(k0 + k) * FF + n0 + bnf * 4;
      float4 va = *(const float4*)wp;
      float4 vb = *(const float4*)(wp + FF);
      const float* fa = (const float*)&va;
      const float* fb = (const float*)&vb;
#pragma unroll
      for (int j = 0; j < 4; ++j) {
        unsigned short ha = bf16r(fa[j]), hb = bf16r(fb[j]);
        unsigned short la = bf16r(fa[j] - __uint_as_float((unsigned)ha << 16));
        unsigned short lb = bf16r(fb[j] - __uint_as_float((unsigned)hb << 16));
        int n = bnf * 4 + j;
        *(unsigned*)&Bh[n][k] = (unsigned)ha | ((unsigned)hb << 16);
        *(unsigned*)&Bl[n][k] = (unsigned)la | ((unsigned)lb << 16);
      }
    }
    __syncthreads();
#pragma unroll
    for (int k2 = 0; k2 < 2; ++k2) {
      int kk = k2 * 32 + lg * 8;
      short8 afh[4], afl[4], bfh[2], bfl[2];
#pragma unroll
      for (int fm = 0; fm < 4; ++fm) {
        afh[fm] = *(const short8*)&Ah[fm * 16 + lr][kk];
        afl[fm] = *(const short8*)&Al[fm * 16 + lr][kk];
      }
#pragma unroll
      for (int fn = 0; fn < 2; ++fn) {
        bfh[fn] = *(const short8*)&Bh[wn + fn * 16 + lr][kk];
        bfl[fn] = *(const short8*)&Bl[wn + fn * 16 + lr][kk];
      }
#pragma unroll
      for (int fm = 0; fm < 4; ++fm)
#pragma unroll
        for (int fn = 0; fn < 2; ++fn) {
          acc[fm][fn] = __builtin_amdgcn_mfma_f32_16x16x32_bf16(afl[fm], bfh[fn], acc[fm][fn], 0, 0, 0);
          acc[fm][fn] = __builtin_amdgcn_mfma_f32_16x16x32_bf16(afh[fm], bfl[fn], acc[fm][fn], 0, 0, 0);
          acc[fm][fn] = __builtin_amdgcn_mfma_f32_16x16x32_bf16(afh[fm], bfh[fn], acc[fm][fn], 0, 0, 0);
        }
    }
  }
  float degf[4][4];
#pragma unroll
  for (int fm = 0; fm < 4; ++fm)
#pragma unroll
    for (int r = 0; r < 4; ++r)
      degf[fm][r] = (float)(deg[m0 + fm * 16 + lg * 4 + r] + 1);  // +1 self loop
  int g = mb >> 2, sub = mb & 3;
#pragma unroll
  for (int fn = 0; fn < 2; ++fn) {
    int col = n0 + wn + fn * 16 + lr;
    float bb = bias[col];
    float cs = 0.f;
#pragma unroll
    for (int fm = 0; fm < 4; ++fm) {
      const float* av = (const float*)&acc[fm][fn];
#pragma unroll
      for (int r = 0; r < 4; ++r) {
        int row = m0 + fm * 16 + lg * 4 + r;
        float v = (av[r] + bb) * degf[fm][r];
        if (C) C[(size_t)row * FF + col] = v;
        cs += v;
      }
    }
    cs += __shfl_xor(cs, 16);
    cs += __shfl_xor(cs, 32);
    if (lg == 0)
      pooled_p[((size_t)sub * 64 + g) * (FF * LL) + lofs + col] = cs;
  }
}

// ---------------- front BN: xt (blocks 0..255, 1024 thr) + pooled (blocks 256..267) ---
__global__ __launch_bounds__(1024, 1) void k_bn_front(const float* __restrict__ x,
                                                      const float* __restrict__ bn_g,
                                                      const float* __restrict__ bn_b,
                                                      const float* __restrict__ pooled_p,
                                                      const int* __restrict__ cnt,
                                                      const float* __restrict__ bnh_g,
                                                      const float* __restrict__ bnh_b,
                                                      ushort_t* __restrict__ zh,
                                                      ushort_t* __restrict__ zl) {
  if (blockIdx.x < 256) {
    __shared__ float sb1[16][256], sb2[16][256];
    __shared__ float rsA[256], bbA[256];
    int i = blockIdx.x, t = threadIdx.x;
    int jq = t & 63, gq = t >> 6;
    int j4 = jq * 4;
    float4 vals[4];
    float s1[4] = {}, s2[4] = {};
#pragma unroll
    for (int r = 0; r < 4; ++r) {
      int g = gq * 4 + r;
      float4 vv = *(const float4*)(x + (size_t)(g * 256 + i) * FF + j4);
      vals[r] = vv;
      s1[0] += vv.x; s2[0] += vv.x * vv.x;
      s1[1] += vv.y; s2[1] += vv.y * vv.y;
      s1[2] += vv.z; s2[2] += vv.z * vv.z;
      s1[3] += vv.w; s2[3] += vv.w * vv.w;
    }
    *(float4*)&sb1[gq][j4] = make_float4(s1[0], s1[1], s1[2], s1[3]);
    *(float4*)&sb2[gq][j4] = make_float4(s2[0], s2[1], s2[2], s2[3]);
    __syncthreads();
    if (t < 256) {
      int j = t;
      float S1 = 0.f, S2 = 0.f;
#pragma unroll
      for (int q = 0; q < 16; ++q) { S1 += sb1[q][j]; S2 += sb2[q][j]; }
      float m = S1 * (1.f / 64.f);
      float var = S2 * (1.f / 64.f) - m * m;
      float rs = 0.f, bb = 0.f;
      if (j > i) {
        int p = i * 255 - (i * (i - 1)) / 2 + (j - i - 1);
        rs = rsqrtf(var + EPSV) * bn_g[p];
        bb = bn_b[p] - m * rs;
      }
      rsA[j] = rs;
      bbA[j] = bb;
    }
    __syncthreads();
    int P0 = i * 255 - (i * (i - 1)) / 2 - i - 1;  // p = P0 + j
#pragma unroll
    for (int r = 0; r < 4; ++r) {
      int g = gq * 4 + r;
      size_t base = (size_t)g * IN1 + P0;
      const float* vf = (const float*)&vals[r];
#pragma unroll
      for (int jj = 0; jj < 4; ++jj) {
        int j = j4 + jj;
        if (j > i) {
          float f = vf[jj] * rsA[j] + bbA[j];
          unsigned short h = bf16r(f);
          zh[base + j] = h;
          zl[base + j] = bf16r(f - __uint_as_float((unsigned)h << 16));
        }
      }
    }
  } else {
    __shared__ float pb1[4][64], pb2[4][64], prs[64], pbb[64];
    int t = threadIdx.x;
    if (t >= 256) return;
    int bx = blockIdx.x - 256;
    int ql = t & 63, gq = t >> 6;
    int q = bx * 64 + ql;
    float vals[16];
    float s1 = 0.f, s2 = 0.f;
#pragma unroll
    for (int gg = 0; gg < 16; ++gg) {
      int g = gq * 16 + gg;
      float v = (pooled_p[((size_t)0 * 64 + g) * (FF * LL) + q] +
                 pooled_p[((size_t)1 * 64 + g) * (FF * LL) + q] +
                 pooled_p[((size_t)2 * 64 + g) * (FF * LL) + q] +
                 pooled_p[((size_t)3 * 64 + g) * (FF * LL) + q]) / (float)cnt[g];
      vals[gg] = v;
      s1 += v;
      s2 += v * v;
    }
    pb1[gq][ql] = s1;
    pb2[gq][ql] = s2;
    __syncthreads();
    if (t < 64) {
      float S1 = pb1[0][t] + pb1[1][t] + pb1[2][t] + pb1[3][t];
      float S2 = pb2[0][t] + pb2[1][t] + pb2[2][t] + pb2[3][t];
      float m = S1 * (1.f / 64.f);
      float var = S2 * (1.f / 64.f) - m * m;
      int qq = bx * 64 + t;
      float rs = rsqrtf(var + EPSV) * bnh_g[qq];
      prs[t] = rs;
      pbb[t] = bnh_b[qq] - m * rs;
    }
    __syncthreads();
#pragma unroll
    for (int gg = 0; gg < 16; ++gg) {
      int g = gq * 16 + gg;
      float f = vals[gg] * prs[ql] + pbb[ql];
      unsigned short h = bf16r(f);
      zh[(size_t)g * IN1 + IU + q] = h;
      zl[(size_t)g * IN1 + IU + q] = bf16r(f - __uint_as_float((unsigned)h << 16));
    }
  }
}

// ---------------- w1 GEMM via MFMA (S=128 -> 1024 blocks = 4/CU) ----------------
__global__ __launch_bounds__(256, 4) void k_w1(const ushort_t* __restrict__ zh,
                                               const ushort_t* __restrict__ zl,
                                               const float* __restrict__ W,
                                               float* __restrict__ partial) {
  __shared__ __align__(16) unsigned short Zh[64][72], Zl[64][72];
  __shared__ __align__(16) unsigned short Wh[64][72], Wl[64][72];
  int nb = blockIdx.x, s = blockIdx.y;
  int t = threadIdx.x;
  int w = t >> 6, l = t & 63, lr = l & 15, lg = l >> 4;
  int ncol = nb * 64 + w * 16 + lr;
  f32x4 acc[4];
#pragma unroll
  for (int mt = 0; mt < 4; ++mt) acc[mt] = (f32x4){0.f, 0.f, 0.f, 0.f};

  for (int c = s; c < 522; c += 128) {  // 33408 = 522*64
    int p0 = c * 64;
    if (c != s) __syncthreads();
#pragma unroll
    for (int it = 0; it < 2; ++it) {
      int idx = it * 256 + t;
      int g = idx >> 3, kq = idx & 7;
      *(uint4*)&Zh[g][kq * 8] = *(const uint4*)(zh + (size_t)g * IN1 + p0 + kq * 8);
      *(uint4*)&Zl[g][kq * 8] = *(const uint4*)(zl + (size_t)g * IN1 + p0 + kq * 8);
    }
#pragma unroll
    for (int it = 0; it < 2; ++it) {
      int idx = it * 256 + t;
      int kp = idx >> 4, cg = idx & 15;
      int k = kp * 2;
      const float* wp = W + (size_t)(p0 + k) * HIDN + nb * 64 + cg * 4;
      float4 va = *(const float4*)wp;
      float4 vb = *(const float4*)(wp + HIDN);
      const float* fa = (const float*)&va;
      const float* fb = (const float*)&vb;
#pragma unroll
      for (int j = 0; j < 4; ++j) {
        unsigned ua = __float_as_uint(fa[j]);
        unsigned ub = __float_as_uint(fb[j]);
        unsigned short ha = (unsigned short)(ua >> 16);
        unsigned short hb = (unsigned short)(ub >> 16);
        unsigned short la = bf16r(fa[j] - __uint_as_float(ua & 0xFFFF0000u));
        unsigned short lb = bf16r(fb[j] - __uint_as_float(ub & 0xFFFF0000u));
        int col = cg * 4 + j;
        *(unsigned*)&Wh[col][k] = (unsigned)ha | ((unsigned)hb << 16);
        *(unsigned*)&Wl[col][k] = (unsigned)la | ((unsigned)lb << 16);
      }
    }
    __syncthreads();
#pragma unroll
    for (int k2 = 0; k2 < 2; ++k2) {
      int kloc = k2 * 32 + lg * 8;
      short8 bh = *(const short8*)&Wh[w * 16 + lr][kloc];
      short8 bl = *(const short8*)&Wl[w * 16 + lr][kloc];
#pragma unroll
      for (int mt = 0; mt < 4; ++mt) {
        short8 ah = *(const short8*)&Zh[mt * 16 + lr][kloc];
        short8 al = *(const short8*)&Zl[mt * 16 + lr][kloc];
        acc[mt] = __builtin_amdgcn_mfma_f32_16x16x32_bf16(al, bh, acc[mt], 0, 0, 0);
        acc[mt] = __builtin_amdgcn_mfma_f32_16x16x32_bf16(ah, bl, acc[mt], 0, 0, 0);
        acc[mt] = __builtin_amdgcn_mfma_f32_16x16x32_bf16(ah, bh, acc[mt], 0, 0, 0);
      }
    }
  }
#pragma unroll
  for (int mt = 0; mt < 4; ++mt) {
    const float* av = (const float*)&acc[mt];
#pragma unroll
    for (int r = 0; r < 4; ++r) {
      int g = mt * 16 + lg * 4 + r;
      partial[((size_t)s * 64 + g) * HIDN + ncol] = av[r];
    }
  }
}

// ---------------- reduce K-splits + bias (128 blocks: wide grid, coalesced) ----------
// (round-10 k_rbn fused this into 8 blocks -> 490us latency disaster; reverted)
__global__ __launch_bounds__(256) void k_reduce(const float* __restrict__ partial,
                                                const float* __restrict__ bias,
                                                float* __restrict__ out, int S, int N) {
  int idx = blockIdx.x * 256 + threadIdx.x;
  if (idx >= 64 * N) return;
  int h = idx % N;
  float a = bias[h];
  for (int s = 0; s < S; ++s) a += partial[(size_t)s * 64 * N + idx];
  out[idx] = a;
}

// ---------------- column-wise BN over 64 rows + ReLU ----------------
__global__ __launch_bounds__(64) void k_bn_relu(const float* __restrict__ in,
                                                const float* __restrict__ gamma,
                                                const float* __restrict__ beta,
                                                float* __restrict__ out, int N) {
  int h = blockIdx.x;
  int g = threadIdx.x;
  float v = in[(size_t)g * N + h];
  float s = v, s2 = v * v;
#pragma unroll
  for (int o = 32; o > 0; o >>= 1) {
    s += __shfl_xor(s, o);
    s2 += __shfl_xor(s2, o);
  }
  float m = s * (1.f / 64.f);
  float var = s2 * (1.f / 64.f) - m * m;
  float r = (v - m) * rsqrtf(var + EPSV) * gamma[h] + beta[h];
  out[(size_t)g * N + h] = fmaxf(r, 0.f);
}

// ---------------- fused small MLP layer: out = relu(BN(Z@W + b)), M=64 ---------------
__global__ __launch_bounds__(256, 2) void k_mlp_small(const float* __restrict__ Z,
                                                      const float* __restrict__ W,
                                                      const float* __restrict__ bias,
                                                      const float* __restrict__ gamma,
                                                      const float* __restrict__ beta,
                                                      float* __restrict__ out, int K, int N) {
  __shared__ float Ws[512 * 16];       // K<=512 rows x 16 cols
  __shared__ float zl[64][132];
  __shared__ float sb1[16][17], sb2[16][17];
  int t = threadIdx.x;
  int h0 = blockIdx.x * 16;
  for (int idx = t; idx < K * 4; idx += 256) {
    int r = idx >> 2, q = idx & 3;
    *(float4*)&Ws[r * 16 + q * 4] = *(const float4*)(W + (size_t)r * N + h0 + q * 4);
  }
  int c = t & 15, gq = t >> 4;         // col c, row-group gq (4 rows each)
  float acc[4] = {};
  for (int ch = 0; ch < K; ch += 128) {
    for (int idx = t; idx < 64 * 32; idx += 256) {
      int g = idx >> 5, kq = idx & 31;
      *(float4*)&zl[g][kq * 4] = *(const float4*)(Z + (size_t)g * K + ch + kq * 4);
    }
    __syncthreads();
#pragma unroll 8
    for (int kk = 0; kk < 128; ++kk) {
      float w = Ws[(ch + kk) * 16 + c];
#pragma unroll
      for (int i = 0; i < 4; ++i) acc[i] = fmaf(zl[gq * 4 + i][kk], w, acc[i]);
    }
    __syncthreads();
  }
  float bb = bias[h0 + c];
  float s1 = 0.f, s2 = 0.f;
#pragma unroll
  for (int i = 0; i < 4; ++i) {
    acc[i] += bb;
    s1 += acc[i];
    s2 += acc[i] * acc[i];
  }
  sb1[gq][c] = s1;
  sb2[gq][c] = s2;
  __syncthreads();
  float S1 = 0.f, S2 = 0.f;
#pragma unroll
  for (int q = 0; q < 16; ++q) { S1 += sb1[q][c]; S2 += sb2[q][c]; }
  float m = S1 * (1.f / 64.f);
  float var = S2 * (1.f / 64.f) - m * m;
  float rs = rsqrtf(var + EPSV) * gamma[h0 + c];
  float be = beta[h0 + c];
#pragma unroll
  for (int i = 0; i < 4; ++i)
    out[(size_t)(gq * 4 + i) * N + h0 + c] = fmaxf((acc[i] - m) * rs + be, 0.f);
}

// ---------------- final: out = A @ w4 + b4, [64,256]@[256,2], wave-parallel ----------
__global__ __launch_bounds__(256) void k_final(const float* __restrict__ A,
                                               const float* __restrict__ w4,
                                               const float* __restrict__ b4,
                                               float* __restrict__ out) {
  __shared__ float w4l[512];
  int t = threadIdx.x;
  w4l[t] = w4[t];
  w4l[256 + t] = w4[256 + t];
  __syncthreads();
  int w = t >> 6, l = t & 63;
  for (int g = w * 16; g < w * 16 + 16; ++g) {
    float4 av = *(const float4*)(A + (size_t)g * 256 + l * 4);
    float c0 = av.x * w4l[(l * 4 + 0) * 2] + av.y * w4l[(l * 4 + 1) * 2] +
               av.z * w4l[(l * 4 + 2) * 2] + av.w * w4l[(l * 4 + 3) * 2];
    float c1 = av.x * w4l[(l * 4 + 0) * 2 + 1] + av.y * w4l[(l * 4 + 1) * 2 + 1] +
               av.z * w4l[(l * 4 + 2) * 2 + 1] + av.w * w4l[(l * 4 + 3) * 2 + 1];
#pragma unroll
    for (int o = 32; o > 0; o >>= 1) {
      c0 += __shfl_xor(c0, o);
      c1 += __shfl_xor(c1, o);
    }
    if (l == 0) {
      out[g * 2 + 0] = c0 + b4[0];
      out[g * 2 + 1] = c1 + b4[1];
    }
  }
}

extern "C" void kernel_launch(void* const* d_in, const int* in_sizes, int n_in,
                              void* d_out, int out_size, void* d_ws, size_t ws_size,
                              hipStream_t stream) {
  const float* x = (const float*)d_in[0];
  const int* edge = (const int*)d_in[1];
  const int* batch = (const int*)d_in[2];
  // d_in[3],[4] lin_src_w/b: dead. d_in[7],[8] att_w/b: dead (softmax over singleton = 1).
  const float* lin_dst_w = (const float*)d_in[5];
  const float* lin_dst_b = (const float*)d_in[6];
  const float* bn_g = (const float*)d_in[9];
  const float* bn_b = (const float*)d_in[10];
  const float* bnh_g = (const float*)d_in[11];
  const float* bnh_b = (const float*)d_in[12];
  const float* w1 = (const float*)d_in[13];
  const float* b1 = (const float*)d_in[14];
  const float* g1 = (const float*)d_in[15];
  const float* be1 = (const float*)d_in[16];
  const float* w2 = (const float*)d_in[17];
  const float* b2 = (const float*)d_in[18];
  const float* g2 = (const float*)d_in[19];
  const float* be2 = (const float*)d_in[20];
  const float* w3 = (const float*)d_in[21];
  const float* b3 = (const float*)d_in[22];
  const float* g3 = (const float*)d_in[23];
  const float* be3 = (const float*)d_in[24];
  const float* w4 = (const float*)d_in[25];
  const float* b4 = (const float*)d_in[26];
  const int* dstp = edge + EE;  // edge_index[1]

  char* ws = (char*)d_ws;
  int* deg = (int*)(ws);                                     // 64 KB (+cnt adjacent)
  int* cnt = (int*)(ws + 65536);                             // 256 B
  float* bufA = (float*)(ws + 131072);                       // 16 MiB
  float* bufB = (float*)(ws + 131072 + 16777216);            // 16 MiB
  float* pooled_p = (float*)(ws + 131072 + 2 * 16777216);    // 4*64*768*4 = 786,432 B
  char* tail = ws + 131072 + 2 * 16777216 + 786432;
  float* m1 = (float*)(tail);                                // 64x512
  float* m1b = (float*)(tail + 131072);
  float* m2b = (float*)(tail + 262144);                      // 64x256
  float* m3b = (float*)(tail + 262144 + 65536);
  // z bf16 pairs live in bufA (h1 region, dead after conv2; h3 store skipped)
  ushort_t* zh = (ushort_t*)bufA;                            // 64*33408*2 = 4.28 MB
  ushort_t* zlp = zh + (size_t)64 * IN1;                     // 4.28 MB
  float* partial = bufB;  // S=128: 128*64*512*4 = 16,777,216 B == bufB exactly

  k_zero<<<65, 256, 0, stream>>>(deg);
  k_hist<<<528, 256, 0, stream>>>(dstp, batch, deg, cnt);

  // ---- 3 conv layers (MFMA bf16-pair), m-major grid for XCD L2 reuse of A ----
  k_conv<<<dim3(256, 2), 256, 0, stream>>>(x, lin_dst_w, lin_dst_b, deg, bufA, pooled_p, 0);
  k_conv<<<dim3(256, 2), 256, 0, stream>>>(bufA, lin_dst_w + (size_t)FF * FF,
                                           lin_dst_b + FF, deg, bufB, pooled_p, FF);
  k_conv<<<dim3(256, 2), 256, 0, stream>>>(bufB, lin_dst_w + (size_t)2 * FF * FF,
                                           lin_dst_b + 2 * FF, deg, (float*)nullptr,
                                           pooled_p, 2 * FF);

  // ---- z = [BN(xt) | BN(sum pooled/cnt)] as bf16 hi/lo (one kernel, 268 blocks) ----
  k_bn_front<<<268, 1024, 0, stream>>>(x, bn_g, bn_b, pooled_p, cnt, bnh_g, bnh_b, zh, zlp);

  // ---- MLP ----
  k_w1<<<dim3(8, 128), 256, 0, stream>>>(zh, zlp, w1, partial);
  k_reduce<<<128, 256, 0, stream>>>(partial, b1, m1, 128, HIDN);
  k_bn_relu<<<HIDN, 64, 0, stream>>>(m1, g1, be1, m1b, HIDN);

  k_mlp_small<<<16, 256, 0, stream>>>(m1b, w2, b2, g2, be2, m2b, HIDN, 256);
  k_mlp_small<<<16, 256, 0, stream>>>(m2b, w3, b3, g3, be3, m3b, 256, 256);

  k_final<<<1, 256, 0, stream>>>(m3b, w4, b4, (float*)d_out);
}

// Round 12
// 173.174 us; speedup vs baseline: 3.6716x; 1.0815x over previous
//
#include <hip/hip_runtime.h>
#include <cstdint>

typedef __attribute__((ext_vector_type(8))) short short8;
typedef __attribute__((ext_vector_type(4))) float f32x4;
typedef unsigned short ushort_t;

static constexpr int NN = 16384, FF = 256, GG = 64, EE = 131072, LL = 3;
static constexpr int HIDN = 512, IU = 32640, IN1 = 33408;
#define EPSV 1e-5f

__device__ inline unsigned short bf16r(float v) {
  unsigned u = __float_as_uint(v);
  u += 0x7FFFu + ((u >> 16) & 1u);
  return (unsigned short)(u >> 16);
}

// ---------------- zero deg+cnt ----------------
__global__ __launch_bounds__(256) void k_zero(int* __restrict__ p) {
  int i = blockIdx.x * 256 + threadIdx.x;
  if (i < 16448) p[i] = 0;  // deg[16384] + cnt[64] contiguous
}

// ---------------- deg histogram + cnt (LDS histogram) ----------------
__global__ __launch_bounds__(256) void k_hist(const int* __restrict__ dst,
                                              const int* __restrict__ batch,
                                              int* __restrict__ deg, int* __restrict__ cnt) {
  __shared__ int hist[64];
  int bx = blockIdx.x, t = threadIdx.x;
  if (bx < 512) {
    int e = bx * 256 + t;
    atomicAdd(&deg[dst[e]], 1);
  } else {
    if (t < 64) hist[t] = 0;
    __syncthreads();
    int4 v = ((const int4*)batch)[(bx - 512) * 256 + t];
    int a[4] = {v.x, v.y, v.z, v.w};
    int cur = a[0], run = 1;
#pragma unroll
    for (int j = 1; j < 4; ++j) {
      if (a[j] == cur) run++;
      else { atomicAdd(&hist[cur], run); cur = a[j]; run = 1; }
    }
    atomicAdd(&hist[cur], run);
    __syncthreads();
    if (t < 64 && hist[t]) atomicAdd(&cnt[t], hist[t]);
  }
}

// ---------------- conv layer via MFMA bf16-pair: C = deg*(A@W+b), fused pooling ------
// SIN=0: A is fp32 (layer 1, x). SIN=1: A is packed u32 (hi16|lo16) from prior conv ->
// staging unpacks with 2 shifts instead of 2x bf16r + fsub per element.
// C output (when Cpk != nullptr) is packed u32 hi|lo.
template <int SIN>
__global__ __launch_bounds__(256, 2) void k_conv(const void* __restrict__ Ap,
                                                 const float* __restrict__ W,
                                                 const float* __restrict__ bias,
                                                 const int* __restrict__ deg,
                                                 unsigned* __restrict__ Cpk,
                                                 float* __restrict__ pooled_p, int lofs) {
  __shared__ __align__(16) unsigned short Ah[64][72], Al[64][72];
  __shared__ __align__(16) unsigned short Bh[128][72], Bl[128][72];
  int n0 = blockIdx.x * 128, m0 = blockIdx.y * 64;
  int t = threadIdx.x;
  int w = t >> 6, l = t & 63;
  int wn = w * 32;
  int lr = l & 15, lg = l >> 4;
  f32x4 acc[4][2];
#pragma unroll
  for (int fm = 0; fm < 4; ++fm)
#pragma unroll
    for (int fn = 0; fn < 2; ++fn) acc[fm][fn] = (f32x4){0.f, 0.f, 0.f, 0.f};

  int am = t >> 2, aq = t & 3;
  int bkp = t & 3, bnf = (t >> 2) & 31, brr = t >> 7;

  for (int ks = 0; ks < 4; ++ks) {
    int k0 = ks * 64;
    if (ks) __syncthreads();
    // ---- stage A tile (64 rows x 64 k) ----
    if (SIN == 0) {
      const float* ap = (const float*)Ap + (size_t)(m0 + am) * FF + k0;
#pragma unroll
      for (int i = 0; i < 4; ++i) {
        int k = aq * 4 + i * 16;
        float4 v = *(const float4*)(ap + k);
        const float* vf = (const float*)&v;
        unsigned short h[4], lo[4];
#pragma unroll
        for (int j = 0; j < 4; ++j) {
          h[j] = bf16r(vf[j]);
          lo[j] = bf16r(vf[j] - __uint_as_float((unsigned)h[j] << 16));
        }
        *(uint2*)&Ah[am][k] = make_uint2((unsigned)h[0] | ((unsigned)h[1] << 16),
                                         (unsigned)h[2] | ((unsigned)h[3] << 16));
        *(uint2*)&Al[am][k] = make_uint2((unsigned)lo[0] | ((unsigned)lo[1] << 16),
                                         (unsigned)lo[2] | ((unsigned)lo[3] << 16));
      }
    } else {
      const unsigned* ap = (const unsigned*)Ap + (size_t)(m0 + am) * FF + k0;
#pragma unroll
      for (int i = 0; i < 4; ++i) {
        int k = aq * 4 + i * 16;
        uint4 v = *(const uint4*)(ap + k);
        const unsigned* vu = (const unsigned*)&v;
        unsigned short h[4], lo[4];
#pragma unroll
        for (int j = 0; j < 4; ++j) {
          h[j] = (unsigned short)(vu[j] >> 16);
          lo[j] = (unsigned short)vu[j];
        }
        *(uint2*)&Ah[am][k] = make_uint2((unsigned)h[0] | ((unsigned)h[1] << 16),
                                         (unsigned)h[2] | ((unsigned)h[3] << 16));
        *(uint2*)&Al[am][k] = make_uint2((unsigned)lo[0] | ((unsigned)lo[1] << 16),
                                         (unsigned)lo[2] | ((unsigned)lo[3] << 16));
      }
    }
    // ---- stage B tile (64 k x 128 n), transposed, fp32 weights split ----
#pragma unroll
    for (int r2 = 0; r2 < 4; ++r2) {
      int k = 2 * bkp + 8 * (brr * 4 + r2);
      const float* wp = W + (size_t)(k0 + k) * FF + n0 + bnf * 4;
      float4 va = *(const float4*)wp;
      float4 vb = *(const float4*)(wp + FF);
      const float* fa = (const float*)&va;
      const float* fb = (const float*)&vb;
#pragma unroll
      for (int j = 0; j < 4; ++j) {
        unsigned short ha = bf16r(fa[j]), hb = bf16r(fb[j]);
        unsigned short la = bf16r(fa[j] - __uint_as_float((unsigned)ha << 16));
        unsigned short lb = bf16r(fb[j] - __uint_as_float((unsigned)hb << 16));
        int n = bnf * 4 + j;
        *(unsigned*)&Bh[n][k] = (unsigned)ha | ((unsigned)hb << 16);
        *(unsigned*)&Bl[n][k] = (unsigned)la | ((unsigned)lb << 16);
      }
    }
    __syncthreads();
#pragma unroll
    for (int k2 = 0; k2 < 2; ++k2) {
      int kk = k2 * 32 + lg * 8;
      short8 afh[4], afl[4], bfh[2], bfl[2];
#pragma unroll
      for (int fm = 0; fm < 4; ++fm) {
        afh[fm] = *(const short8*)&Ah[fm * 16 + lr][kk];
        afl[fm] = *(const short8*)&Al[fm * 16 + lr][kk];
      }
#pragma unroll
      for (int fn = 0; fn < 2; ++fn) {
        bfh[fn] = *(const short8*)&Bh[wn + fn * 16 + lr][kk];
        bfl[fn] = *(const short8*)&Bl[wn + fn * 16 + lr][kk];
      }
#pragma unroll
      for (int fm = 0; fm < 4; ++fm)
#pragma unroll
        for (int fn = 0; fn < 2; ++fn) {
          acc[fm][fn] = __builtin_amdgcn_mfma_f32_16x16x32_bf16(afl[fm], bfh[fn], acc[fm][fn], 0, 0, 0);
          acc[fm][fn] = __builtin_amdgcn_mfma_f32_16x16x32_bf16(afh[fm], bfl[fn], acc[fm][fn], 0, 0, 0);
          acc[fm][fn] = __builtin_amdgcn_mfma_f32_16x16x32_bf16(afh[fm], bfh[fn], acc[fm][fn], 0, 0, 0);
        }
    }
  }
  float degf[4][4];
#pragma unroll
  for (int fm = 0; fm < 4; ++fm)
#pragma unroll
    for (int r = 0; r < 4; ++r)
      degf[fm][r] = (float)(deg[m0 + fm * 16 + lg * 4 + r] + 1);  // +1 self loop
  int g = blockIdx.y >> 2, sub = blockIdx.y & 3;
#pragma unroll
  for (int fn = 0; fn < 2; ++fn) {
    int col = n0 + wn + fn * 16 + lr;
    float bb = bias[col];
    float cs = 0.f;
#pragma unroll
    for (int fm = 0; fm < 4; ++fm) {
      const float* av = (const float*)&acc[fm][fn];
#pragma unroll
      for (int r = 0; r < 4; ++r) {
        int row = m0 + fm * 16 + lg * 4 + r;
        float v = (av[r] + bb) * degf[fm][r];
        cs += v;
        if (Cpk) {
          unsigned uv = __float_as_uint(v);
          unsigned hi = uv & 0xFFFF0000u;
          unsigned short lo16 = bf16r(v - __uint_as_float(hi));
          Cpk[(size_t)row * FF + col] = hi | (unsigned)lo16;
        }
      }
    }
    cs += __shfl_xor(cs, 16);
    cs += __shfl_xor(cs, 32);
    if (lg == 0)
      pooled_p[((size_t)sub * 64 + g) * (FF * LL) + lofs + col] = cs;
  }
}

// ---------------- front BN: xt (blocks 0..255, 1024 thr) + pooled (blocks 256..267) ---
__global__ __launch_bounds__(1024, 1) void k_bn_front(const float* __restrict__ x,
                                                      const float* __restrict__ bn_g,
                                                      const float* __restrict__ bn_b,
                                                      const float* __restrict__ pooled_p,
                                                      const int* __restrict__ cnt,
                                                      const float* __restrict__ bnh_g,
                                                      const float* __restrict__ bnh_b,
                                                      ushort_t* __restrict__ zh,
                                                      ushort_t* __restrict__ zl) {
  if (blockIdx.x < 256) {
    __shared__ float sb1[16][256], sb2[16][256];
    __shared__ float rsA[256], bbA[256];
    int i = blockIdx.x, t = threadIdx.x;
    int jq = t & 63, gq = t >> 6;
    int j4 = jq * 4;
    float4 vals[4];
    float s1[4] = {}, s2[4] = {};
#pragma unroll
    for (int r = 0; r < 4; ++r) {
      int g = gq * 4 + r;
      float4 vv = *(const float4*)(x + (size_t)(g * 256 + i) * FF + j4);
      vals[r] = vv;
      s1[0] += vv.x; s2[0] += vv.x * vv.x;
      s1[1] += vv.y; s2[1] += vv.y * vv.y;
      s1[2] += vv.z; s2[2] += vv.z * vv.z;
      s1[3] += vv.w; s2[3] += vv.w * vv.w;
    }
    *(float4*)&sb1[gq][j4] = make_float4(s1[0], s1[1], s1[2], s1[3]);
    *(float4*)&sb2[gq][j4] = make_float4(s2[0], s2[1], s2[2], s2[3]);
    __syncthreads();
    if (t < 256) {
      int j = t;
      float S1 = 0.f, S2 = 0.f;
#pragma unroll
      for (int q = 0; q < 16; ++q) { S1 += sb1[q][j]; S2 += sb2[q][j]; }
      float m = S1 * (1.f / 64.f);
      float var = S2 * (1.f / 64.f) - m * m;
      float rs = 0.f, bb = 0.f;
      if (j > i) {
        int p = i * 255 - (i * (i - 1)) / 2 + (j - i - 1);
        rs = rsqrtf(var + EPSV) * bn_g[p];
        bb = bn_b[p] - m * rs;
      }
      rsA[j] = rs;
      bbA[j] = bb;
    }
    __syncthreads();
    int P0 = i * 255 - (i * (i - 1)) / 2 - i - 1;  // p = P0 + j
#pragma unroll
    for (int r = 0; r < 4; ++r) {
      int g = gq * 4 + r;
      size_t base = (size_t)g * IN1 + P0;
      const float* vf = (const float*)&vals[r];
#pragma unroll
      for (int jj = 0; jj < 4; ++jj) {
        int j = j4 + jj;
        if (j > i) {
          float f = vf[jj] * rsA[j] + bbA[j];
          unsigned short h = bf16r(f);
          zh[base + j] = h;
          zl[base + j] = bf16r(f - __uint_as_float((unsigned)h << 16));
        }
      }
    }
  } else {
    __shared__ float pb1[4][64], pb2[4][64], prs[64], pbb[64];
    int t = threadIdx.x;
    if (t >= 256) return;
    int bx = blockIdx.x - 256;
    int ql = t & 63, gq = t >> 6;
    int q = bx * 64 + ql;
    float vals[16];
    float s1 = 0.f, s2 = 0.f;
#pragma unroll
    for (int gg = 0; gg < 16; ++gg) {
      int g = gq * 16 + gg;
      float v = (pooled_p[((size_t)0 * 64 + g) * (FF * LL) + q] +
                 pooled_p[((size_t)1 * 64 + g) * (FF * LL) + q] +
                 pooled_p[((size_t)2 * 64 + g) * (FF * LL) + q] +
                 pooled_p[((size_t)3 * 64 + g) * (FF * LL) + q]) / (float)cnt[g];
      vals[gg] = v;
      s1 += v;
      s2 += v * v;
    }
    pb1[gq][ql] = s1;
    pb2[gq][ql] = s2;
    __syncthreads();
    if (t < 64) {
      float S1 = pb1[0][t] + pb1[1][t] + pb1[2][t] + pb1[3][t];
      float S2 = pb2[0][t] + pb2[1][t] + pb2[2][t] + pb2[3][t];
      float m = S1 * (1.f / 64.f);
      float var = S2 * (1.f / 64.f) - m * m;
      int qq = bx * 64 + t;
      float rs = rsqrtf(var + EPSV) * bnh_g[qq];
      prs[t] = rs;
      pbb[t] = bnh_b[qq] - m * rs;
    }
    __syncthreads();
#pragma unroll
    for (int gg = 0; gg < 16; ++gg) {
      int g = gq * 16 + gg;
      float f = vals[gg] * prs[ql] + pbb[ql];
      unsigned short h = bf16r(f);
      zh[(size_t)g * IN1 + IU + q] = h;
      zl[(size_t)g * IN1 + IU + q] = bf16r(f - __uint_as_float((unsigned)h << 16));
    }
  }
}

// ---------------- w1 GEMM via MFMA (S=64, partial 8.4 MB) ----------------
__global__ __launch_bounds__(256, 4) void k_w1(const ushort_t* __restrict__ zh,
                                               const ushort_t* __restrict__ zl,
                                               const float* __restrict__ W,
                                               float* __restrict__ partial) {
  __shared__ __align__(16) unsigned short Zh[64][72], Zl[64][72];
  __shared__ __align__(16) unsigned short Wh[64][72], Wl[64][72];
  int nb = blockIdx.x, s = blockIdx.y;
  int t = threadIdx.x;
  int w = t >> 6, l = t & 63, lr = l & 15, lg = l >> 4;
  int ncol = nb * 64 + w * 16 + lr;
  f32x4 acc[4];
#pragma unroll
  for (int mt = 0; mt < 4; ++mt) acc[mt] = (f32x4){0.f, 0.f, 0.f, 0.f};

  for (int c = s; c < 522; c += 64) {  // 33408 = 522*64
    int p0 = c * 64;
    if (c != s) __syncthreads();
#pragma unroll
    for (int it = 0; it < 2; ++it) {
      int idx = it * 256 + t;
      int g = idx >> 3, kq = idx & 7;
      *(uint4*)&Zh[g][kq * 8] = *(const uint4*)(zh + (size_t)g * IN1 + p0 + kq * 8);
      *(uint4*)&Zl[g][kq * 8] = *(const uint4*)(zl + (size_t)g * IN1 + p0 + kq * 8);
    }
#pragma unroll
    for (int it = 0; it < 2; ++it) {
      int idx = it * 256 + t;
      int kp = idx >> 4, cg = idx & 15;
      int k = kp * 2;
      const float* wp = W + (size_t)(p0 + k) * HIDN + nb * 64 + cg * 4;
      float4 va = *(const float4*)wp;
      float4 vb = *(const float4*)(wp + HIDN);
      const float* fa = (const float*)&va;
      const float* fb = (const float*)&vb;
#pragma unroll
      for (int j = 0; j < 4; ++j) {
        unsigned ua = __float_as_uint(fa[j]);
        unsigned ub = __float_as_uint(fb[j]);
        unsigned short ha = (unsigned short)(ua >> 16);
        unsigned short hb = (unsigned short)(ub >> 16);
        unsigned short la = bf16r(fa[j] - __uint_as_float(ua & 0xFFFF0000u));
        unsigned short lb = bf16r(fb[j] - __uint_as_float(ub & 0xFFFF0000u));
        int col = cg * 4 + j;
        *(unsigned*)&Wh[col][k] = (unsigned)ha | ((unsigned)hb << 16);
        *(unsigned*)&Wl[col][k] = (unsigned)la | ((unsigned)lb << 16);
      }
    }
    __syncthreads();
#pragma unroll
    for (int k2 = 0; k2 < 2; ++k2) {
      int kloc = k2 * 32 + lg * 8;
      short8 bh = *(const short8*)&Wh[w * 16 + lr][kloc];
      short8 bl = *(const short8*)&Wl[w * 16 + lr][kloc];
#pragma unroll
      for (int mt = 0; mt < 4; ++mt) {
        short8 ah = *(const short8*)&Zh[mt * 16 + lr][kloc];
        short8 al = *(const short8*)&Zl[mt * 16 + lr][kloc];
        acc[mt] = __builtin_amdgcn_mfma_f32_16x16x32_bf16(al, bh, acc[mt], 0, 0, 0);
        acc[mt] = __builtin_amdgcn_mfma_f32_16x16x32_bf16(ah, bl, acc[mt], 0, 0, 0);
        acc[mt] = __builtin_amdgcn_mfma_f32_16x16x32_bf16(ah, bh, acc[mt], 0, 0, 0);
      }
    }
  }
#pragma unroll
  for (int mt = 0; mt < 4; ++mt) {
    const float* av = (const float*)&acc[mt];
#pragma unroll
    for (int r = 0; r < 4; ++r) {
      int g = mt * 16 + lg * 4 + r;
      partial[((size_t)s * 64 + g) * HIDN + ncol] = av[r];
    }
  }
}

// ---------------- reduce K-splits + bias (wide grid, coalesced) ----------
__global__ __launch_bounds__(256) void k_reduce(const float* __restrict__ partial,
                                                const float* __restrict__ bias,
                                                float* __restrict__ out, int S, int N) {
  int idx = blockIdx.x * 256 + threadIdx.x;
  if (idx >= 64 * N) return;
  int h = idx % N;
  float a = bias[h];
  for (int s = 0; s < S; ++s) a += partial[(size_t)s * 64 * N + idx];
  out[idx] = a;
}

// ---------------- fused small MLP layer: out = relu(BN(relu(BN_in(Z))@W + b)) --------
// INBN=1: apply column BN (ibn_g/ibn_b) + ReLU to the staged z chunk in LDS (stats
// over the 64 g-rows, which are all present per chunk) -> replaces k_bn_relu.
template <int INBN>
__global__ __launch_bounds__(256, 2) void k_mlp_small(const float* __restrict__ Z,
                                                      const float* __restrict__ ibn_g,
                                                      const float* __restrict__ ibn_b,
                                                      const float* __restrict__ W,
                                                      const float* __restrict__ bias,
                                                      const float* __restrict__ gamma,
                                                      const float* __restrict__ beta,
                                                      float* __restrict__ out, int K, int N) {
  __shared__ float Ws[512 * 16];       // K<=512 rows x 16 cols
  __shared__ float zl[64][132];
  __shared__ float sb1[16][17], sb2[16][17];
  int t = threadIdx.x;
  int h0 = blockIdx.x * 16;
  for (int idx = t; idx < K * 4; idx += 256) {
    int r = idx >> 2, q = idx & 3;
    *(float4*)&Ws[r * 16 + q * 4] = *(const float4*)(W + (size_t)r * N + h0 + q * 4);
  }
  int c = t & 15, gq = t >> 4;         // col c, row-group gq (4 rows each)
  float acc[4] = {};
  for (int ch = 0; ch < K; ch += 128) {
    for (int idx = t; idx < 64 * 32; idx += 256) {
      int g = idx >> 5, kq = idx & 31;
      *(float4*)&zl[g][kq * 4] = *(const float4*)(Z + (size_t)g * K + ch + kq * 4);
    }
    __syncthreads();
    if (INBN) {
      if (t < 128) {
        float s1 = 0.f, s2 = 0.f;
#pragma unroll
        for (int g = 0; g < 64; ++g) {
          float v = zl[g][t];
          s1 += v;
          s2 += v * v;
        }
        float m = s1 * (1.f / 64.f);
        float var = s2 * (1.f / 64.f) - m * m;
        float rs = rsqrtf(var + EPSV) * ibn_g[ch + t];
        float bb = ibn_b[ch + t] - m * rs;
#pragma unroll
        for (int g = 0; g < 64; ++g)
          zl[g][t] = fmaxf(zl[g][t] * rs + bb, 0.f);
      }
      __syncthreads();
    }
#pragma unroll 8
    for (int kk = 0; kk < 128; ++kk) {
      float w = Ws[(ch + kk) * 16 + c];
#pragma unroll
      for (int i = 0; i < 4; ++i) acc[i] = fmaf(zl[gq * 4 + i][kk], w, acc[i]);
    }
    __syncthreads();
  }
  float bb = bias[h0 + c];
  float s1 = 0.f, s2 = 0.f;
#pragma unroll
  for (int i = 0; i < 4; ++i) {
    acc[i] += bb;
    s1 += acc[i];
    s2 += acc[i] * acc[i];
  }
  sb1[gq][c] = s1;
  sb2[gq][c] = s2;
  __syncthreads();
  float S1 = 0.f, S2 = 0.f;
#pragma unroll
  for (int q = 0; q < 16; ++q) { S1 += sb1[q][c]; S2 += sb2[q][c]; }
  float m = S1 * (1.f / 64.f);
  float var = S2 * (1.f / 64.f) - m * m;
  float rs = rsqrtf(var + EPSV) * gamma[h0 + c];
  float be = beta[h0 + c];
#pragma unroll
  for (int i = 0; i < 4; ++i)
    out[(size_t)(gq * 4 + i) * N + h0 + c] = fmaxf((acc[i] - m) * rs + be, 0.f);
}

// ---------------- final: out = A @ w4 + b4, [64,256]@[256,2], wave-parallel ----------
__global__ __launch_bounds__(256) void k_final(const float* __restrict__ A,
                                               const float* __restrict__ w4,
                                               const float* __restrict__ b4,
                                               float* __restrict__ out) {
  __shared__ float w4l[512];
  int t = threadIdx.x;
  w4l[t] = w4[t];
  w4l[256 + t] = w4[256 + t];
  __syncthreads();
  int w = t >> 6, l = t & 63;
  for (int g = w * 16; g < w * 16 + 16; ++g) {
    float4 av = *(const float4*)(A + (size_t)g * 256 + l * 4);
    float c0 = av.x * w4l[(l * 4 + 0) * 2] + av.y * w4l[(l * 4 + 1) * 2] +
               av.z * w4l[(l * 4 + 2) * 2] + av.w * w4l[(l * 4 + 3) * 2];
    float c1 = av.x * w4l[(l * 4 + 0) * 2 + 1] + av.y * w4l[(l * 4 + 1) * 2 + 1] +
               av.z * w4l[(l * 4 + 2) * 2 + 1] + av.w * w4l[(l * 4 + 3) * 2 + 1];
#pragma unroll
    for (int o = 32; o > 0; o >>= 1) {
      c0 += __shfl_xor(c0, o);
      c1 += __shfl_xor(c1, o);
    }
    if (l == 0) {
      out[g * 2 + 0] = c0 + b4[0];
      out[g * 2 + 1] = c1 + b4[1];
    }
  }
}

extern "C" void kernel_launch(void* const* d_in, const int* in_sizes, int n_in,
                              void* d_out, int out_size, void* d_ws, size_t ws_size,
                              hipStream_t stream) {
  const float* x = (const float*)d_in[0];
  const int* edge = (const int*)d_in[1];
  const int* batch = (const int*)d_in[2];
  // d_in[3],[4] lin_src_w/b: dead. d_in[7],[8] att_w/b: dead (softmax over singleton = 1).
  const float* lin_dst_w = (const float*)d_in[5];
  const float* lin_dst_b = (const float*)d_in[6];
  const float* bn_g = (const float*)d_in[9];
  const float* bn_b = (const float*)d_in[10];
  const float* bnh_g = (const float*)d_in[11];
  const float* bnh_b = (const float*)d_in[12];
  const float* w1 = (const float*)d_in[13];
  const float* b1 = (const float*)d_in[14];
  const float* g1 = (const float*)d_in[15];
  const float* be1 = (const float*)d_in[16];
  const float* w2 = (const float*)d_in[17];
  const float* b2 = (const float*)d_in[18];
  const float* g2 = (const float*)d_in[19];
  const float* be2 = (const float*)d_in[20];
  const float* w3 = (const float*)d_in[21];
  const float* b3 = (const float*)d_in[22];
  const float* g3 = (const float*)d_in[23];
  const float* be3 = (const float*)d_in[24];
  const float* w4 = (const float*)d_in[25];
  const float* b4 = (const float*)d_in[26];
  const int* dstp = edge + EE;  // edge_index[1]

  char* ws = (char*)d_ws;
  int* deg = (int*)(ws);                                     // 64 KB (+cnt adjacent)
  int* cnt = (int*)(ws + 65536);                             // 256 B
  float* bufA = (float*)(ws + 131072);                       // 16 MiB
  float* bufB = (float*)(ws + 131072 + 16777216);            // 16 MiB
  float* pooled_p = (float*)(ws + 131072 + 2 * 16777216);    // 4*64*768*4 = 786,432 B
  char* tail = ws + 131072 + 2 * 16777216 + 786432;
  float* m1 = (float*)(tail);                                // 64x512
  float* m2b = (float*)(tail + 131072);                      // 64x256
  float* m3b = (float*)(tail + 131072 + 65536);
  // z bf16 pairs live in bufA (h1 region, dead after conv2; h3 store skipped)
  ushort_t* zh = (ushort_t*)bufA;                            // 64*33408*2 = 4.28 MB
  ushort_t* zlp = zh + (size_t)64 * IN1;                     // 4.28 MB
  float* partial = bufB;  // S=64: 64*64*512*4 = 8.4 MB

  k_zero<<<65, 256, 0, stream>>>(deg);
  k_hist<<<528, 256, 0, stream>>>(dstp, batch, deg, cnt);

  // ---- 3 conv layers (MFMA bf16-pair); h passed as packed u32 hi|lo between layers --
  k_conv<0><<<dim3(2, 256), 256, 0, stream>>>(x, lin_dst_w, lin_dst_b, deg,
                                              (unsigned*)bufA, pooled_p, 0);
  k_conv<1><<<dim3(2, 256), 256, 0, stream>>>(bufA, lin_dst_w + (size_t)FF * FF,
                                              lin_dst_b + FF, deg, (unsigned*)bufB,
                                              pooled_p, FF);
  k_conv<1><<<dim3(2, 256), 256, 0, stream>>>(bufB, lin_dst_w + (size_t)2 * FF * FF,
                                              lin_dst_b + 2 * FF, deg, (unsigned*)nullptr,
                                              pooled_p, 2 * FF);

  // ---- z = [BN(xt) | BN(sum pooled/cnt)] as bf16 hi/lo ----
  k_bn_front<<<268, 1024, 0, stream>>>(x, bn_g, bn_b, pooled_p, cnt, bnh_g, bnh_b, zh, zlp);

  // ---- MLP ----
  k_w1<<<dim3(8, 64), 256, 0, stream>>>(zh, zlp, w1, partial);
  k_reduce<<<128, 256, 0, stream>>>(partial, b1, m1, 64, HIDN);

  k_mlp_small<1><<<16, 256, 0, stream>>>(m1, g1, be1, w2, b2, g2, be2, m2b, HIDN, 256);
  k_mlp_small<0><<<16, 256, 0, stream>>>(m2b, nullptr, nullptr, w3, b3, g3, be3, m3b, 256, 256);

  k_final<<<1, 256, 0, stream>>>(m3b, w4, b4, (float*)d_out);
}